// Round 1
// baseline (639.498 us; speedup 1.0000x reference)
//
#include <hip/hip_runtime.h>
#include <math.h>

#define N_ENT   50000
#define N_REL   500
#define N_EDGE  800000
#define H       96
#define BN_EPS  1e-5f

// ---- order-preserving float <-> uint for atomicMax over signed floats ----
__device__ __forceinline__ unsigned flipf(float f) {
    unsigned u = __float_as_uint(f);
    return (u & 0x80000000u) ? ~u : (u | 0x80000000u);
}
__device__ __forceinline__ float unflipf(unsigned u) {
    return (u & 0x80000000u) ? __uint_as_float(u & 0x7fffffffu)
                             : __uint_as_float(~u);
}

// ---- zero a region of workspace (ws is poisoned 0xAA before every call) ----
__global__ void k_zero(unsigned* __restrict__ p, int n) {
    int i = blockIdx.x * blockDim.x + threadIdx.x;
    if (i < n) p[i] = 0u;
}

// ---- 1 thread / edge: score = rel_row . ent_row ; atomicMax into seg_max ----
__global__ __launch_bounds__(256) void k_score(
        const float* __restrict__ ent, const float* __restrict__ rel,
        const int* __restrict__ rel_id, const int* __restrict__ dst,
        float* __restrict__ score, unsigned* __restrict__ seg_max) {
    int e = blockIdx.x * blockDim.x + threadIdx.x;
    if (e >= N_EDGE) return;
    int d = dst[e];
    const float4* r = (const float4*)(rel + (size_t)rel_id[e] * H);
    const float4* v = (const float4*)(ent + (size_t)d * H);
    float acc = 0.0f;
#pragma unroll
    for (int i = 0; i < H / 4; ++i) {
        float4 a = r[i], b = v[i];
        acc += a.x * b.x + a.y * b.y + a.z * b.z + a.w * b.w;
    }
    score[e] = acc;
    atomicMax(seg_max + d, flipf(acc));
}

// ---- w = exp(score - max); atomicAdd into seg_sum; store w over score ----
__global__ __launch_bounds__(256) void k_expw(
        const int* __restrict__ dst, float* __restrict__ score,
        const unsigned* __restrict__ seg_max, float* __restrict__ seg_sum) {
    int e = blockIdx.x * blockDim.x + threadIdx.x;
    if (e >= N_EDGE) return;
    int d = dst[e];
    float m = unflipf(seg_max[d]);
    float w = expf(score[e] - m);
    score[e] = w;
    atomicAdd(seg_sum + d, w);
}

// ---- neigh[dst[e]][d] += rel[rel_id[e]][d] * alpha ; 1 thread / (edge,dim) ----
__global__ __launch_bounds__(256) void k_scatter(
        const float* __restrict__ rel, const int* __restrict__ rel_id,
        const int* __restrict__ dst, const float* __restrict__ w,
        const float* __restrict__ seg_sum, float* __restrict__ neigh) {
    int t = blockIdx.x * blockDim.x + threadIdx.x;   // < 76.8M, fits int32
    if (t >= N_EDGE * H) return;
    int e = t / H;
    int d = t - e * H;
    int n = dst[e];
    float alpha = w[e] / seg_sum[n];
    atomicAdd(neigh + (size_t)n * H + d, rel[(size_t)rel_id[e] * H + d] * alpha);
}

// ---- out = neigh @ W  (50000 x 96 x 96), W staged in LDS ----
__global__ __launch_bounds__(256) void k_gemm(
        const float* __restrict__ neigh, const float* __restrict__ W,
        float* __restrict__ out) {
    __shared__ float Ws[H * H];
    for (int i = threadIdx.x; i < H * H; i += 256) Ws[i] = W[i];
    __syncthreads();
    int t = blockIdx.x * 256 + threadIdx.x;          // one output element
    if (t >= N_ENT * H) return;
    int n = t / H;
    int d = t - n * H;
    const float4* nr4 = (const float4*)(neigh + (size_t)n * H);
    float4 row[H / 4];
#pragma unroll
    for (int i = 0; i < H / 4; ++i) row[i] = nr4[i];
    float acc = 0.0f;
#pragma unroll
    for (int i = 0; i < H / 4; ++i) {
        acc += row[i].x * Ws[(4 * i + 0) * H + d];
        acc += row[i].y * Ws[(4 * i + 1) * H + d];
        acc += row[i].z * Ws[(4 * i + 2) * H + d];
        acc += row[i].w * Ws[(4 * i + 3) * H + d];
    }
    out[t] = acc;
}

// ---- per-column sum / sumsq with block-private accumulation ----
__global__ void k_bnstats(const float* __restrict__ out,
                          float* __restrict__ bn_sum, float* __restrict__ bn_sumsq) {
    int d = threadIdx.x;          // blockDim.x = 128, only d < 96 active
    if (d >= H) return;
    float s = 0.0f, ss = 0.0f;
    for (int n = blockIdx.x; n < N_ENT; n += gridDim.x) {
        float v = out[(size_t)n * H + d];
        s += v;
        ss += v * v;
    }
    atomicAdd(bn_sum + d, s);
    atomicAdd(bn_sumsq + d, ss);
}

// ---- apply BN (batch stats) + tanh in place ----
__global__ __launch_bounds__(256) void k_bnapply(
        float* __restrict__ out, const float* __restrict__ bn_sum,
        const float* __restrict__ bn_sumsq, const float* __restrict__ gamma,
        const float* __restrict__ beta) {
    int t = blockIdx.x * 256 + threadIdx.x;
    if (t >= N_ENT * H) return;
    int d = t % H;
    const float inv_n = 1.0f / (float)N_ENT;
    float mu = bn_sum[d] * inv_n;
    float var = bn_sumsq[d] * inv_n - mu * mu;
    float x = (out[t] - mu) * rsqrtf(var + BN_EPS) * gamma[d] + beta[d];
    out[t] = tanhf(x);
}

extern "C" void kernel_launch(void* const* d_in, const int* in_sizes, int n_in,
                              void* d_out, int out_size, void* d_ws, size_t ws_size,
                              hipStream_t stream) {
    const float* ent   = (const float*)d_in[0];   // [50000,96]
    const float* rel   = (const float*)d_in[1];   // [500,96]
    const float* W     = (const float*)d_in[2];   // [96,96]
    const float* gamma = (const float*)d_in[3];   // [96]
    const float* beta  = (const float*)d_in[4];   // [96]
    const int* rel_id  = (const int*)d_in[5];     // [800000]
    const int* dst     = (const int*)d_in[6];     // [800000]
    float* out = (float*)d_out;                   // [50000,96]

    // workspace layout (floats): score/w [E] | seg_max [N](uint) | seg_sum [N]
    //                            | neigh [N*H] | bn_sum [H] | bn_sumsq [H]
    float*    ws      = (float*)d_ws;
    float*    score   = ws;
    unsigned* seg_max = (unsigned*)(ws + N_EDGE);
    float*    seg_sum = ws + N_EDGE + N_ENT;
    float*    neigh   = ws + N_EDGE + 2 * N_ENT;
    float*    bn_sum  = neigh + (size_t)N_ENT * H;
    float*    bn_sumsq= bn_sum + H;

    // zero seg_max, seg_sum, neigh, bn arrays (everything after score)
    int zcount = 2 * N_ENT + N_ENT * H + 2 * H;
    k_zero<<<(zcount + 255) / 256, 256, 0, stream>>>((unsigned*)(ws + N_EDGE), zcount);

    k_score<<<(N_EDGE + 255) / 256, 256, 0, stream>>>(ent, rel, rel_id, dst, score, seg_max);
    k_expw <<<(N_EDGE + 255) / 256, 256, 0, stream>>>(dst, score, seg_max, seg_sum);
    k_scatter<<<(N_EDGE * H + 255) / 256, 256, 0, stream>>>(rel, rel_id, dst, score, seg_sum, neigh);
    k_gemm<<<(N_ENT * H + 255) / 256, 256, 0, stream>>>(neigh, W, out);
    k_bnstats<<<512, 128, 0, stream>>>(out, bn_sum, bn_sumsq);
    k_bnapply<<<(N_ENT * H + 255) / 256, 256, 0, stream>>>(out, bn_sum, bn_sumsq, gamma, beta);
}

// Round 2
// 587.656 us; speedup vs baseline: 1.0882x; 1.0882x over previous
//
#include <hip/hip_runtime.h>
#include <math.h>

#define N_ENT   50000
#define N_REL   500
#define N_EDGE  800000
#define H       96
#define BN_EPS  1e-5f
#define SCAN_T  1024
#define CHUNK   49          // 1024*49 = 50176 >= 50000

// ---- zero a region of workspace ----
__global__ void k_zero(unsigned* __restrict__ p, int n) {
    int i = blockIdx.x * blockDim.x + threadIdx.x;
    if (i < n) p[i] = 0u;
}

// ---- relW = rel_emb @ W  (500 x 96 x 96), W staged in LDS ----
__global__ __launch_bounds__(256) void k_relw(
        const float* __restrict__ rel, const float* __restrict__ W,
        float* __restrict__ relW) {
    __shared__ float Ws[H * H];
    for (int i = threadIdx.x; i < H * H; i += 256) Ws[i] = W[i];
    __syncthreads();
    int t = blockIdx.x * 256 + threadIdx.x;
    if (t >= N_REL * H) return;
    int r = t / H;
    int c = t - r * H;
    const float4* rr = (const float4*)(rel + (size_t)r * H);
    float acc = 0.0f;
#pragma unroll
    for (int i = 0; i < H / 4; ++i) {
        float4 a = rr[i];
        acc += a.x * Ws[(4 * i + 0) * H + c];
        acc += a.y * Ws[(4 * i + 1) * H + c];
        acc += a.z * Ws[(4 * i + 2) * H + c];
        acc += a.w * Ws[(4 * i + 3) * H + c];
    }
    relW[t] = acc;
}

// ---- 1 thread / edge: score = rel_row . ent_row ; histogram deg[dst]++ ----
__global__ __launch_bounds__(256) void k_score(
        const float* __restrict__ ent, const float* __restrict__ rel,
        const int* __restrict__ rel_id, const int* __restrict__ dst,
        float* __restrict__ score, int* __restrict__ deg) {
    int e = blockIdx.x * blockDim.x + threadIdx.x;
    if (e >= N_EDGE) return;
    int d = dst[e];
    const float4* r = (const float4*)(rel + (size_t)rel_id[e] * H);
    const float4* v = (const float4*)(ent + (size_t)d * H);
    float acc = 0.0f;
#pragma unroll
    for (int i = 0; i < H / 4; ++i) {
        float4 a = r[i], b = v[i];
        acc += a.x * b.x + a.y * b.y + a.z * b.z + a.w * b.w;
    }
    score[e] = acc;
    atomicAdd(deg + d, 1);
}

// ---- single-block exclusive scan of deg -> row_ptr ----
__global__ __launch_bounds__(SCAN_T) void k_scan(
        const int* __restrict__ deg, int* __restrict__ row_ptr) {
    __shared__ int sums[SCAN_T];
    int t = threadIdx.x;
    int base = t * CHUNK;
    int s = 0;
    for (int i = 0; i < CHUNK; ++i) {
        int idx = base + i;
        if (idx < N_ENT) s += deg[idx];
    }
    sums[t] = s;
    __syncthreads();
    // Hillis-Steele inclusive scan
    for (int off = 1; off < SCAN_T; off <<= 1) {
        int v = (t >= off) ? sums[t - off] : 0;
        __syncthreads();
        sums[t] += v;
        __syncthreads();
    }
    int run = (t == 0) ? 0 : sums[t - 1];
    for (int i = 0; i < CHUNK; ++i) {
        int idx = base + i;
        if (idx < N_ENT) {
            row_ptr[idx] = run;
            run += deg[idx];
        }
    }
}

// ---- bucket edges into CSR order: eidx[row_ptr[d] + cursor[d]++] = e ----
__global__ __launch_bounds__(256) void k_bucket(
        const int* __restrict__ dst, const int* __restrict__ row_ptr,
        int* __restrict__ cursor, int* __restrict__ eidx) {
    int e = blockIdx.x * blockDim.x + threadIdx.x;
    if (e >= N_EDGE) return;
    int d = dst[e];
    int pos = row_ptr[d] + atomicAdd(cursor + d, 1);
    eidx[pos] = e;
}

// ---- per (node, dim): softmax over node's edges + weighted sum of relW ----
__global__ __launch_bounds__(256) void k_aggregate(
        const float* __restrict__ score, const int* __restrict__ eidx,
        const int* __restrict__ row_ptr, const int* __restrict__ deg,
        const int* __restrict__ rel_id, const float* __restrict__ relW,
        float* __restrict__ out) {
    int t = blockIdx.x * 256 + threadIdx.x;
    if (t >= N_ENT * H) return;
    int n = t / H;
    int dim = t - n * H;
    int start = row_ptr[n];
    int cnt = deg[n];
    if (cnt == 0) { out[t] = 0.0f; return; }
    float m = -INFINITY;
    for (int j = 0; j < cnt; ++j)
        m = fmaxf(m, score[eidx[start + j]]);
    float acc = 0.0f, wsum = 0.0f;
    for (int j = 0; j < cnt; ++j) {
        int e = eidx[start + j];
        float w = expf(score[e] - m);
        wsum += w;
        acc += w * relW[(size_t)rel_id[e] * H + dim];
    }
    out[t] = acc / wsum;
}

// ---- per-column sum / sumsq with block-private accumulation ----
__global__ void k_bnstats(const float* __restrict__ out,
                          float* __restrict__ bn_sum, float* __restrict__ bn_sumsq) {
    int d = threadIdx.x;          // blockDim.x = 128, only d < 96 active
    if (d >= H) return;
    float s = 0.0f, ss = 0.0f;
    for (int n = blockIdx.x; n < N_ENT; n += gridDim.x) {
        float v = out[(size_t)n * H + d];
        s += v;
        ss += v * v;
    }
    atomicAdd(bn_sum + d, s);
    atomicAdd(bn_sumsq + d, ss);
}

// ---- apply BN (batch stats) + tanh in place ----
__global__ __launch_bounds__(256) void k_bnapply(
        float* __restrict__ out, const float* __restrict__ bn_sum,
        const float* __restrict__ bn_sumsq, const float* __restrict__ gamma,
        const float* __restrict__ beta) {
    int t = blockIdx.x * 256 + threadIdx.x;
    if (t >= N_ENT * H) return;
    int d = t % H;
    const float inv_n = 1.0f / (float)N_ENT;
    float mu = bn_sum[d] * inv_n;
    float var = bn_sumsq[d] * inv_n - mu * mu;
    float x = (out[t] - mu) * rsqrtf(var + BN_EPS) * gamma[d] + beta[d];
    out[t] = tanhf(x);
}

extern "C" void kernel_launch(void* const* d_in, const int* in_sizes, int n_in,
                              void* d_out, int out_size, void* d_ws, size_t ws_size,
                              hipStream_t stream) {
    const float* ent   = (const float*)d_in[0];   // [50000,96]
    const float* rel   = (const float*)d_in[1];   // [500,96]
    const float* W     = (const float*)d_in[2];   // [96,96]
    const float* gamma = (const float*)d_in[3];   // [96]
    const float* beta  = (const float*)d_in[4];   // [96]
    const int* rel_id  = (const int*)d_in[5];     // [800000]
    const int* dst     = (const int*)d_in[6];     // [800000]
    float* out = (float*)d_out;                   // [50000,96] fp32

    // ws layout (4B units):
    // score [E] | eidx [E] | row_ptr [N] | ZERO{ deg [N] | cursor [N] |
    //   bn_sum [H] | bn_sumsq [H] } | relW [500*96]
    float* ws       = (float*)d_ws;
    float* score    = ws;
    int*   eidx     = (int*)(ws + N_EDGE);
    int*   row_ptr  = (int*)(ws + 2 * N_EDGE);
    int*   zbase    = (int*)(ws + 2 * N_EDGE + N_ENT);
    int*   deg      = zbase;
    int*   cursor   = zbase + N_ENT;
    float* bn_sum   = (float*)(zbase + 2 * N_ENT);
    float* bn_sumsq = bn_sum + H;
    float* relW     = bn_sumsq + H;

    const int zcount = 2 * N_ENT + 2 * H;
    k_zero<<<(zcount + 255) / 256, 256, 0, stream>>>((unsigned*)zbase, zcount);

    k_relw <<<(N_REL * H + 255) / 256, 256, 0, stream>>>(rel, W, relW);
    k_score<<<(N_EDGE + 255) / 256, 256, 0, stream>>>(ent, rel, rel_id, dst, score, deg);
    k_scan <<<1, SCAN_T, 0, stream>>>(deg, row_ptr);
    k_bucket<<<(N_EDGE + 255) / 256, 256, 0, stream>>>(dst, row_ptr, cursor, eidx);
    k_aggregate<<<(N_ENT * H + 255) / 256, 256, 0, stream>>>(
        score, eidx, row_ptr, deg, rel_id, relW, out);
    k_bnstats<<<512, 128, 0, stream>>>(out, bn_sum, bn_sumsq);
    k_bnapply<<<(N_ENT * H + 255) / 256, 256, 0, stream>>>(out, bn_sum, bn_sumsq, gamma, beta);
}

// Round 3
// 380.946 us; speedup vs baseline: 1.6787x; 1.5426x over previous
//
#include <hip/hip_runtime.h>
#include <math.h>

#define N_ENT   50000
#define N_REL   500
#define N_EDGE  800000
#define H       96
#define BN_EPS  1e-5f
#define SCAN_T  1024
#define CHUNK   49          // 1024*49 = 50176 >= 50000

// ---- zero a region of workspace ----
__global__ void k_zero(unsigned* __restrict__ p, int n) {
    int i = blockIdx.x * blockDim.x + threadIdx.x;
    if (i < n) p[i] = 0u;
}

// ---- relW = rel_emb @ W  (500 x 96 x 96), W staged in LDS ----
__global__ __launch_bounds__(256) void k_relw(
        const float* __restrict__ rel, const float* __restrict__ W,
        float* __restrict__ relW) {
    __shared__ float Ws[H * H];
    for (int i = threadIdx.x; i < H * H; i += 256) Ws[i] = W[i];
    __syncthreads();
    int t = blockIdx.x * 256 + threadIdx.x;
    if (t >= N_REL * H) return;
    int r = t / H;
    int c = t - r * H;
    const float4* rr = (const float4*)(rel + (size_t)r * H);
    float acc = 0.0f;
#pragma unroll
    for (int i = 0; i < H / 4; ++i) {
        float4 a = rr[i];
        acc += a.x * Ws[(4 * i + 0) * H + c];
        acc += a.y * Ws[(4 * i + 1) * H + c];
        acc += a.z * Ws[(4 * i + 2) * H + c];
        acc += a.w * Ws[(4 * i + 3) * H + c];
    }
    relW[t] = acc;
}

// ---- 8 lanes / edge: score = rel_row . ent_row ; histogram deg[dst]++ ----
// each lane loads 3 float4s: 8 lanes * 48B interleaved = 128B-aligned chunks
__global__ __launch_bounds__(256) void k_score(
        const float* __restrict__ ent, const float* __restrict__ rel,
        const int* __restrict__ rel_id, const int* __restrict__ dst,
        float* __restrict__ score, int* __restrict__ deg) {
    int tid = blockIdx.x * 256 + threadIdx.x;
    int e = tid >> 3;
    int q = tid & 7;
    if (e >= N_EDGE) return;
    int d = dst[e];
    const float4* r = (const float4*)(rel + (size_t)rel_id[e] * H);
    const float4* v = (const float4*)(ent + (size_t)d * H);
    float acc = 0.0f;
#pragma unroll
    for (int i = 0; i < 3; ++i) {            // lane q reads float4 q+8i
        float4 a = r[q + 8 * i];
        float4 b = v[q + 8 * i];
        acc += a.x * b.x + a.y * b.y + a.z * b.z + a.w * b.w;
    }
    acc += __shfl_xor(acc, 1);
    acc += __shfl_xor(acc, 2);
    acc += __shfl_xor(acc, 4);
    if (q == 0) {
        score[e] = acc;
        atomicAdd(deg + d, 1);
    }
}

// ---- single-block exclusive scan of deg -> row_ptr ----
__global__ __launch_bounds__(SCAN_T) void k_scan(
        const int* __restrict__ deg, int* __restrict__ row_ptr) {
    __shared__ int sums[SCAN_T];
    int t = threadIdx.x;
    int base = t * CHUNK;
    int s = 0;
    for (int i = 0; i < CHUNK; ++i) {
        int idx = base + i;
        if (idx < N_ENT) s += deg[idx];
    }
    sums[t] = s;
    __syncthreads();
    for (int off = 1; off < SCAN_T; off <<= 1) {
        int v = (t >= off) ? sums[t - off] : 0;
        __syncthreads();
        sums[t] += v;
        __syncthreads();
    }
    int run = (t == 0) ? 0 : sums[t - 1];
    for (int i = 0; i < CHUNK; ++i) {
        int idx = base + i;
        if (idx < N_ENT) {
            row_ptr[idx] = run;
            run += deg[idx];
        }
    }
}

// ---- bucket edge PAYLOADS into CSR order (rid, score) ----
__global__ __launch_bounds__(256) void k_bucket(
        const int* __restrict__ dst, const int* __restrict__ rel_id,
        const float* __restrict__ score, const int* __restrict__ row_ptr,
        int* __restrict__ cursor, int* __restrict__ rid_s,
        float* __restrict__ score_s) {
    int e = blockIdx.x * blockDim.x + threadIdx.x;
    if (e >= N_EDGE) return;
    int d = dst[e];
    int pos = row_ptr[d] + atomicAdd(cursor + d, 1);
    rid_s[pos] = rel_id[e];
    score_s[pos] = score[e];
}

// ---- per node: softmax over contiguous score_s segment -> alpha in place ----
__global__ __launch_bounds__(256) void k_alpha(
        const int* __restrict__ row_ptr, const int* __restrict__ deg,
        float* __restrict__ score_s) {
    int n = blockIdx.x * 256 + threadIdx.x;
    if (n >= N_ENT) return;
    int start = row_ptr[n];
    int cnt = deg[n];
    float m = -INFINITY;
    for (int j = 0; j < cnt; ++j) m = fmaxf(m, score_s[start + j]);
    float s = 0.0f;
    for (int j = 0; j < cnt; ++j) {
        float w = expf(score_s[start + j] - m);
        score_s[start + j] = w;
        s += w;
    }
    float inv = 1.0f / s;
    for (int j = 0; j < cnt; ++j) score_s[start + j] *= inv;
}

// ---- per (node, dim): out = sum_j alpha_j * relW[rid_j][dim], unroll 4 ----
__global__ __launch_bounds__(256) void k_aggregate(
        const float* __restrict__ alpha_s, const int* __restrict__ rid_s,
        const int* __restrict__ row_ptr, const int* __restrict__ deg,
        const float* __restrict__ relW, float* __restrict__ out) {
    int t = blockIdx.x * 256 + threadIdx.x;
    if (t >= N_ENT * H) return;
    int n = t / H;
    int dim = t - n * H;
    int start = row_ptr[n];
    int cnt = deg[n];
    float acc = 0.0f;
    int j = 0;
    for (; j + 4 <= cnt; j += 4) {
        int r0 = rid_s[start + j + 0];
        int r1 = rid_s[start + j + 1];
        int r2 = rid_s[start + j + 2];
        int r3 = rid_s[start + j + 3];
        float a0 = alpha_s[start + j + 0];
        float a1 = alpha_s[start + j + 1];
        float a2 = alpha_s[start + j + 2];
        float a3 = alpha_s[start + j + 3];
        float v0 = relW[r0 * H + dim];
        float v1 = relW[r1 * H + dim];
        float v2 = relW[r2 * H + dim];
        float v3 = relW[r3 * H + dim];
        acc += a0 * v0 + a1 * v1 + a2 * v2 + a3 * v3;
    }
    for (; j < cnt; ++j)
        acc += alpha_s[start + j] * relW[rid_s[start + j] * H + dim];
    out[t] = acc;
}

// ---- per-column sum / sumsq with block-private accumulation ----
__global__ void k_bnstats(const float* __restrict__ out,
                          float* __restrict__ bn_sum, float* __restrict__ bn_sumsq) {
    int d = threadIdx.x;          // blockDim.x = 128, only d < 96 active
    if (d >= H) return;
    float s = 0.0f, ss = 0.0f;
    for (int n = blockIdx.x; n < N_ENT; n += gridDim.x) {
        float v = out[(size_t)n * H + d];
        s += v;
        ss += v * v;
    }
    atomicAdd(bn_sum + d, s);
    atomicAdd(bn_sumsq + d, ss);
}

// ---- apply BN (batch stats) + tanh in place ----
__global__ __launch_bounds__(256) void k_bnapply(
        float* __restrict__ out, const float* __restrict__ bn_sum,
        const float* __restrict__ bn_sumsq, const float* __restrict__ gamma,
        const float* __restrict__ beta) {
    int t = blockIdx.x * 256 + threadIdx.x;
    if (t >= N_ENT * H) return;
    int d = t % H;
    const float inv_n = 1.0f / (float)N_ENT;
    float mu = bn_sum[d] * inv_n;
    float var = bn_sumsq[d] * inv_n - mu * mu;
    float x = (out[t] - mu) * rsqrtf(var + BN_EPS) * gamma[d] + beta[d];
    out[t] = tanhf(x);
}

extern "C" void kernel_launch(void* const* d_in, const int* in_sizes, int n_in,
                              void* d_out, int out_size, void* d_ws, size_t ws_size,
                              hipStream_t stream) {
    const float* ent   = (const float*)d_in[0];   // [50000,96]
    const float* rel   = (const float*)d_in[1];   // [500,96]
    const float* W     = (const float*)d_in[2];   // [96,96]
    const float* gamma = (const float*)d_in[3];   // [96]
    const float* beta  = (const float*)d_in[4];   // [96]
    const int* rel_id  = (const int*)d_in[5];     // [800000]
    const int* dst     = (const int*)d_in[6];     // [800000]
    float* out = (float*)d_out;                   // [50000,96] fp32

    // ws layout (4B units):
    // score [E] | rid_s [E] | score_s/alpha_s [E] | row_ptr [N] |
    // ZERO{ deg [N] | cursor [N] | bn_sum [H] | bn_sumsq [H] } | relW [500*96]
    float* ws       = (float*)d_ws;
    float* score    = ws;
    int*   rid_s    = (int*)(ws + N_EDGE);
    float* score_s  = ws + 2 * N_EDGE;
    int*   row_ptr  = (int*)(ws + 3 * N_EDGE);
    int*   zbase    = (int*)(ws + 3 * N_EDGE + N_ENT);
    int*   deg      = zbase;
    int*   cursor   = zbase + N_ENT;
    float* bn_sum   = (float*)(zbase + 2 * N_ENT);
    float* bn_sumsq = bn_sum + H;
    float* relW     = bn_sumsq + H;

    const int zcount = 2 * N_ENT + 2 * H;
    k_zero<<<(zcount + 255) / 256, 256, 0, stream>>>((unsigned*)zbase, zcount);

    k_relw <<<(N_REL * H + 255) / 256, 256, 0, stream>>>(rel, W, relW);
    k_score<<<(N_EDGE * 8 + 255) / 256, 256, 0, stream>>>(ent, rel, rel_id, dst, score, deg);
    k_scan <<<1, SCAN_T, 0, stream>>>(deg, row_ptr);
    k_bucket<<<(N_EDGE + 255) / 256, 256, 0, stream>>>(dst, rel_id, score, row_ptr, cursor, rid_s, score_s);
    k_alpha<<<(N_ENT + 255) / 256, 256, 0, stream>>>(row_ptr, deg, score_s);
    k_aggregate<<<(N_ENT * H + 255) / 256, 256, 0, stream>>>(
        score_s, rid_s, row_ptr, deg, relW, out);
    k_bnstats<<<512, 128, 0, stream>>>(out, bn_sum, bn_sumsq);
    k_bnapply<<<(N_ENT * H + 255) / 256, 256, 0, stream>>>(out, bn_sum, bn_sumsq, gamma, beta);
}

// Round 4
// 292.211 us; speedup vs baseline: 2.1885x; 1.3037x over previous
//
#include <hip/hip_runtime.h>
#include <math.h>

#define N_ENT   50000
#define N_REL   500
#define N_EDGE  800000
#define H       96
#define BN_EPS  1e-5f
#define SCAN_B  1024
#define NBLK    ((N_ENT + SCAN_B - 1) / SCAN_B)   // 49 <= 64

// ---- zero a region of workspace ----
__global__ void k_zero(unsigned* __restrict__ p, int n) {
    int i = blockIdx.x * blockDim.x + threadIdx.x;
    if (i < n) p[i] = 0u;
}

// ---- relW = rel_emb @ W  (500 x 96 x 96), W staged in LDS ----
__global__ __launch_bounds__(256) void k_relw(
        const float* __restrict__ rel, const float* __restrict__ W,
        float* __restrict__ relW) {
    __shared__ float Ws[H * H];
    for (int i = threadIdx.x; i < H * H; i += 256) Ws[i] = W[i];
    __syncthreads();
    int t = blockIdx.x * 256 + threadIdx.x;
    if (t >= N_REL * H) return;
    int r = t / H;
    int c = t - r * H;
    const float4* rr = (const float4*)(rel + (size_t)r * H);
    float acc = 0.0f;
#pragma unroll
    for (int i = 0; i < H / 4; ++i) {
        float4 a = rr[i];
        acc += a.x * Ws[(4 * i + 0) * H + c];
        acc += a.y * Ws[(4 * i + 1) * H + c];
        acc += a.z * Ws[(4 * i + 2) * H + c];
        acc += a.w * Ws[(4 * i + 3) * H + c];
    }
    relW[t] = acc;
}

// ---- 8 lanes / edge: score = rel_row . ent_row ; histogram deg[dst]++ ----
__global__ __launch_bounds__(256) void k_score(
        const float* __restrict__ ent, const float* __restrict__ rel,
        const int* __restrict__ rel_id, const int* __restrict__ dst,
        float* __restrict__ score, int* __restrict__ deg) {
    int tid = blockIdx.x * 256 + threadIdx.x;
    int e = tid >> 3;
    int q = tid & 7;
    if (e >= N_EDGE) return;
    int d = dst[e];
    const float4* r = (const float4*)(rel + (size_t)rel_id[e] * H);
    const float4* v = (const float4*)(ent + (size_t)d * H);
    float acc = 0.0f;
#pragma unroll
    for (int i = 0; i < 3; ++i) {            // lane q reads float4 q+8i
        float4 a = r[q + 8 * i];
        float4 b = v[q + 8 * i];
        acc += a.x * b.x + a.y * b.y + a.z * b.z + a.w * b.w;
    }
    acc += __shfl_xor(acc, 1);
    acc += __shfl_xor(acc, 2);
    acc += __shfl_xor(acc, 4);
    if (q == 0) {
        score[e] = acc;
        atomicAdd(deg + d, 1);
    }
}

// ---- scan phase 1: per-block LDS Hillis-Steele, exclusive within block ----
__global__ __launch_bounds__(SCAN_B) void k_scan1(
        const int* __restrict__ deg, int* __restrict__ row_ptr,
        int* __restrict__ blk_sum) {
    __shared__ int sh[SCAN_B];
    int t = threadIdx.x;
    int g = blockIdx.x * SCAN_B + t;
    int v = (g < N_ENT) ? deg[g] : 0;
    sh[t] = v;
    __syncthreads();
    for (int off = 1; off < SCAN_B; off <<= 1) {
        int u = (t >= off) ? sh[t - off] : 0;
        __syncthreads();
        sh[t] += u;
        __syncthreads();
    }
    if (g < N_ENT) row_ptr[g] = sh[t] - v;   // exclusive
    if (t == SCAN_B - 1) blk_sum[blockIdx.x] = sh[t];
}

// ---- scan phase 2: one wave shuffle-scans the 49 block sums ----
__global__ __launch_bounds__(64) void k_scan2(int* __restrict__ blk_sum) {
    int t = threadIdx.x;
    int v = (t < NBLK) ? blk_sum[t] : 0;
    for (int off = 1; off < 64; off <<= 1) {
        int u = __shfl_up(v, off);
        if (t >= off) v += u;
    }
    int ex = __shfl_up(v, 1);
    if (t == 0) ex = 0;
    if (t < NBLK) blk_sum[t] = ex;
}

// ---- scan phase 3: add block offsets ----
__global__ __launch_bounds__(SCAN_B) void k_scan3(
        int* __restrict__ row_ptr, const int* __restrict__ blk_sum) {
    int g = blockIdx.x * SCAN_B + threadIdx.x;
    if (g < N_ENT) row_ptr[g] += blk_sum[blockIdx.x];
}

// ---- bucket edge PAYLOADS into CSR order (rid, score) ----
__global__ __launch_bounds__(256) void k_bucket(
        const int* __restrict__ dst, const int* __restrict__ rel_id,
        const float* __restrict__ score, const int* __restrict__ row_ptr,
        int* __restrict__ cursor, int* __restrict__ rid_s,
        float* __restrict__ score_s) {
    int e = blockIdx.x * blockDim.x + threadIdx.x;
    if (e >= N_EDGE) return;
    int d = dst[e];
    int pos = row_ptr[d] + atomicAdd(cursor + d, 1);
    rid_s[pos] = rel_id[e];
    score_s[pos] = score[e];
}

// ---- per node: softmax over contiguous score_s segment -> alpha in place ----
__global__ __launch_bounds__(256) void k_alpha(
        const int* __restrict__ row_ptr, const int* __restrict__ deg,
        float* __restrict__ score_s) {
    int n = blockIdx.x * 256 + threadIdx.x;
    if (n >= N_ENT) return;
    int start = row_ptr[n];
    int cnt = deg[n];
    float m = -INFINITY;
    for (int j = 0; j < cnt; ++j) m = fmaxf(m, score_s[start + j]);
    float s = 0.0f;
    for (int j = 0; j < cnt; ++j) {
        float w = expf(score_s[start + j] - m);
        score_s[start + j] = w;
        s += w;
    }
    float inv = 1.0f / s;
    for (int j = 0; j < cnt; ++j) score_s[start + j] *= inv;
}

// ---- per (node, dim): out = sum_j alpha_j * relW[rid_j][dim], unroll 4 ----
__global__ __launch_bounds__(256) void k_aggregate(
        const float* __restrict__ alpha_s, const int* __restrict__ rid_s,
        const int* __restrict__ row_ptr, const int* __restrict__ deg,
        const float* __restrict__ relW, float* __restrict__ out) {
    int t = blockIdx.x * 256 + threadIdx.x;
    if (t >= N_ENT * H) return;
    int n = t / H;
    int dim = t - n * H;
    int start = row_ptr[n];
    int cnt = deg[n];
    float acc = 0.0f;
    int j = 0;
    for (; j + 4 <= cnt; j += 4) {
        int r0 = rid_s[start + j + 0];
        int r1 = rid_s[start + j + 1];
        int r2 = rid_s[start + j + 2];
        int r3 = rid_s[start + j + 3];
        float a0 = alpha_s[start + j + 0];
        float a1 = alpha_s[start + j + 1];
        float a2 = alpha_s[start + j + 2];
        float a3 = alpha_s[start + j + 3];
        float v0 = relW[r0 * H + dim];
        float v1 = relW[r1 * H + dim];
        float v2 = relW[r2 * H + dim];
        float v3 = relW[r3 * H + dim];
        acc += a0 * v0 + a1 * v1 + a2 * v2 + a3 * v3;
    }
    for (; j < cnt; ++j)
        acc += alpha_s[start + j] * relW[rid_s[start + j] * H + dim];
    out[t] = acc;
}

// ---- per-column sum / sumsq with block-private accumulation ----
__global__ void k_bnstats(const float* __restrict__ out,
                          float* __restrict__ bn_sum, float* __restrict__ bn_sumsq) {
    int d = threadIdx.x;          // blockDim.x = 128, only d < 96 active
    if (d >= H) return;
    float s = 0.0f, ss = 0.0f;
    for (int n = blockIdx.x; n < N_ENT; n += gridDim.x) {
        float v = out[(size_t)n * H + d];
        s += v;
        ss += v * v;
    }
    atomicAdd(bn_sum + d, s);
    atomicAdd(bn_sumsq + d, ss);
}

// ---- apply BN (batch stats) + tanh in place ----
__global__ __launch_bounds__(256) void k_bnapply(
        float* __restrict__ out, const float* __restrict__ bn_sum,
        const float* __restrict__ bn_sumsq, const float* __restrict__ gamma,
        const float* __restrict__ beta) {
    int t = blockIdx.x * 256 + threadIdx.x;
    if (t >= N_ENT * H) return;
    int d = t % H;
    const float inv_n = 1.0f / (float)N_ENT;
    float mu = bn_sum[d] * inv_n;
    float var = bn_sumsq[d] * inv_n - mu * mu;
    float x = (out[t] - mu) * rsqrtf(var + BN_EPS) * gamma[d] + beta[d];
    out[t] = tanhf(x);
}

extern "C" void kernel_launch(void* const* d_in, const int* in_sizes, int n_in,
                              void* d_out, int out_size, void* d_ws, size_t ws_size,
                              hipStream_t stream) {
    const float* ent   = (const float*)d_in[0];   // [50000,96]
    const float* rel   = (const float*)d_in[1];   // [500,96]
    const float* W     = (const float*)d_in[2];   // [96,96]
    const float* gamma = (const float*)d_in[3];   // [96]
    const float* beta  = (const float*)d_in[4];   // [96]
    const int* rel_id  = (const int*)d_in[5];     // [800000]
    const int* dst     = (const int*)d_in[6];     // [800000]
    float* out = (float*)d_out;                   // [50000,96] fp32

    // ws layout (4B units):
    // score [E] | rid_s [E] | score_s/alpha_s [E] | row_ptr [N] |
    // ZERO{ deg [N] | cursor [N] | bn_sum [H] | bn_sumsq [H] } |
    // relW [500*96] | blk_sum [NBLK]
    float* ws       = (float*)d_ws;
    float* score    = ws;
    int*   rid_s    = (int*)(ws + N_EDGE);
    float* score_s  = ws + 2 * N_EDGE;
    int*   row_ptr  = (int*)(ws + 3 * N_EDGE);
    int*   zbase    = (int*)(ws + 3 * N_EDGE + N_ENT);
    int*   deg      = zbase;
    int*   cursor   = zbase + N_ENT;
    float* bn_sum   = (float*)(zbase + 2 * N_ENT);
    float* bn_sumsq = bn_sum + H;
    float* relW     = bn_sumsq + H;
    int*   blk_sum  = (int*)(relW + N_REL * H);

    const int zcount = 2 * N_ENT + 2 * H;
    k_zero<<<(zcount + 255) / 256, 256, 0, stream>>>((unsigned*)zbase, zcount);

    k_relw <<<(N_REL * H + 255) / 256, 256, 0, stream>>>(rel, W, relW);
    k_score<<<(N_EDGE * 8 + 255) / 256, 256, 0, stream>>>(ent, rel, rel_id, dst, score, deg);
    k_scan1<<<NBLK, SCAN_B, 0, stream>>>(deg, row_ptr, blk_sum);
    k_scan2<<<1, 64, 0, stream>>>(blk_sum);
    k_scan3<<<NBLK, SCAN_B, 0, stream>>>(row_ptr, blk_sum);
    k_bucket<<<(N_EDGE + 255) / 256, 256, 0, stream>>>(dst, rel_id, score, row_ptr, cursor, rid_s, score_s);
    k_alpha<<<(N_ENT + 255) / 256, 256, 0, stream>>>(row_ptr, deg, score_s);
    k_aggregate<<<(N_ENT * H + 255) / 256, 256, 0, stream>>>(
        score_s, rid_s, row_ptr, deg, relW, out);
    k_bnstats<<<512, 128, 0, stream>>>(out, bn_sum, bn_sumsq);
    k_bnapply<<<(N_ENT * H + 255) / 256, 256, 0, stream>>>(out, bn_sum, bn_sumsq, gamma, beta);
}